// Round 5
// baseline (495.487 us; speedup 1.0000x reference)
//
#include <hip/hip_runtime.h>
#include <math.h>

#define B_ 16
#define H_ 16
#define M_ 256
#define N_ 576
#define D_ 1024
#define BK 64
#define LDS_STRIDE (BK + 8)
#define NROWS (B_ * N_ + B_ * M_)         // 13312 feature rows
#define SL_UNITS (B_ * M_ * N_ / 4)       // 589824 float4 units
#define GEMM_BLOCKS (B_ * 4 * 9)          // 576 tiles
#define SUMLOG_BLK (SL_UNITS / 256)       // 2304

constexpr float EPS_ = 1e-8f;
constexpr float FI_ = 0.90909090909090906f;   // RHO/(RHO+EPSILON) = 1/1.1

typedef __bf16 bf16x8 __attribute__((ext_vector_type(8)));
typedef float f32x4 __attribute__((ext_vector_type(4)));

__device__ __forceinline__ float wave_reduce(float v) {
#pragma unroll
  for (int o = 32; o > 0; o >>= 1) v += __shfl_down(v, o, 64);
  return v;
}

__device__ __forceinline__ unsigned short f2bf(float f) {
  union { float f; unsigned u; } a; a.f = f;
  unsigned r = a.u + 0x7fff + ((a.u >> 16) & 1);   // RNE
  return (unsigned short)(r >> 16);
}

__device__ __forceinline__ float bf2f(unsigned short u) {
  union { unsigned u; float f; } a; a.u = ((unsigned)u) << 16;
  return a.f;
}

// L2-normalize+bf16-cast vis (B*N rows) and txt (B*M rows), one wave per row;
// trailing 4 blocks: masksum[b], vv := 1.0, and barrier counters := 0
// (stream order guarantees visibility to the sink launches).
__global__ __launch_bounds__(256) void prep_kernel(const float* __restrict__ vis,
                                                   const float* __restrict__ txt,
                                                   const float* __restrict__ mask,
                                                   unsigned short* __restrict__ xb,
                                                   unsigned short* __restrict__ yb,
                                                   float* __restrict__ masksum,
                                                   float* __restrict__ vv,
                                                   int* __restrict__ ctr) {
  const int bid = blockIdx.x;
  const int lane = threadIdx.x & 63;
  if (bid < NROWS / 4) {
    int wave = bid * 4 + (threadIdx.x >> 6);
    const float* src;
    unsigned short* dst;
    if (wave < B_ * N_) {
      src = vis + (size_t)wave * D_;
      dst = xb + (size_t)wave * D_;
    } else {
      int r = wave - B_ * N_;
      src = txt + (size_t)r * D_;
      dst = yb + (size_t)r * D_;
    }
    float4 v[4];
    float s = 0.f;
#pragma unroll
    for (int it = 0; it < 4; ++it) {
      v[it] = *(const float4*)&src[it * 256 + lane * 4];
      s += v[it].x * v[it].x + v[it].y * v[it].y + v[it].z * v[it].z + v[it].w * v[it].w;
    }
    s = wave_reduce(s);
    s = __shfl(s, 0, 64);
    float inv = rsqrtf(s + 1e-12f);
#pragma unroll
    for (int it = 0; it < 4; ++it) {
      ushort4 pk;
      pk.x = f2bf(v[it].x * inv);
      pk.y = f2bf(v[it].y * inv);
      pk.z = f2bf(v[it].z * inv);
      pk.w = f2bf(v[it].w * inv);
      *(ushort4*)&dst[it * 256 + lane * 4] = pk;
    }
  } else {
    const int g = bid - NROWS / 4;                       // 0..3
    if (g == 0 && threadIdx.x < 96) ctr[threadIdx.x] = 0;
    for (int i = threadIdx.x; i < 4 * N_; i += 256) vv[g * 4 * N_ + i] = 1.f;
    int b = g * 4 + (threadIdx.x >> 6);                  // 0..15
    float4 mv = *(const float4*)&mask[b * M_ + lane * 4];
    float s = wave_reduce(mv.x + mv.y + mv.z + mv.w);
    if (lane == 0) masksum[b] = s;
  }
}

// One launch, two block roles:
//   blocks 0..575:    K[b,m,n] = bf16(exp(10*(dot(y,x)-1))), 64x64 MFMA tile
//   blocks 576..2879: SL = sum_h log(student+EPS), 1 float4/thread
//                     (HBM-bound; overlaps the MFMA blocks)
__global__ __launch_bounds__(256) void gemm_sumlog_kernel(
    const unsigned short* __restrict__ xb, const unsigned short* __restrict__ yb,
    const float* __restrict__ student, unsigned short* __restrict__ Kw,
    float* __restrict__ SL) {
  __shared__ unsigned short As[64][LDS_STRIDE];  // y rows (m)
  __shared__ unsigned short Bs[64][LDS_STRIDE];  // x rows (n)

  if (blockIdx.x >= GEMM_BLOCKS) {
    const int unit = (blockIdx.x - GEMM_BLOCKS) * 256 + threadIdx.x;  // 0..589823
    const int b = unit / (M_ * N_ / 4);
    const int cb = unit - b * (M_ * N_ / 4);
    const float* st = student + (size_t)b * H_ * M_ * N_ + (size_t)cb * 4;
    float4 acc = {0.f, 0.f, 0.f, 0.f};
#pragma unroll
    for (int h = 0; h < H_; ++h) {
      float4 s4 = *(const float4*)&st[(size_t)h * M_ * N_];
      acc.x += __logf(s4.x + EPS_);
      acc.y += __logf(s4.y + EPS_);
      acc.z += __logf(s4.z + EPS_);
      acc.w += __logf(s4.w + EPS_);
    }
    *(float4*)&SL[(size_t)b * M_ * N_ + (size_t)cb * 4] = acc;
    return;
  }

  const int tile = blockIdx.x;
  const int b = tile / 36;
  const int rem = tile - b * 36;
  const int m0 = (rem / 9) * 64;
  const int n0 = (rem - (rem / 9) * 9) * 64;
  const unsigned short* Y = yb + (size_t)b * M_ * D_;
  const unsigned short* X = xb + (size_t)b * N_ * D_;
  const int t = threadIdx.x;
  const int lane = t & 63;
  const int w = t >> 6;
  const int wm = (w & 1) * 32;
  const int wn = (w >> 1) * 32;
  const int lr = t >> 3;           // 0..31 staging row
  const int lc = (t & 7) * 8;      // staging col (bf16 units, 16B chunks)
  const int fr = lane & 15;        // fragment row within 16
  const int fk = (lane >> 4) * 8;  // fragment k offset

  f32x4 acc[2][2] = {};
  for (int k0 = 0; k0 < D_; k0 += BK) {
#pragma unroll
    for (int p = 0; p < 2; ++p) {
      *(uint4*)&As[lr + 32 * p][lc] = *(const uint4*)&Y[(size_t)(m0 + lr + 32 * p) * D_ + k0 + lc];
      *(uint4*)&Bs[lr + 32 * p][lc] = *(const uint4*)&X[(size_t)(n0 + lr + 32 * p) * D_ + k0 + lc];
    }
    __syncthreads();
#pragma unroll
    for (int ks = 0; ks < BK; ks += 32) {
      bf16x8 a[2], bfr[2];
#pragma unroll
      for (int i = 0; i < 2; ++i) {
        a[i] = *(const bf16x8*)&As[wm + i * 16 + fr][ks + fk];
        bfr[i] = *(const bf16x8*)&Bs[wn + i * 16 + fr][ks + fk];
      }
#pragma unroll
      for (int i = 0; i < 2; ++i)
#pragma unroll
        for (int j = 0; j < 2; ++j)
          acc[i][j] = __builtin_amdgcn_mfma_f32_16x16x32_bf16(a[i], bfr[j], acc[i][j], 0, 0, 0);
    }
    __syncthreads();
  }

  // C/D layout: m = (lane>>4)*4 + reg, n = lane&15
  const int cm = (lane >> 4) * 4;
  const int cn = lane & 15;
#pragma unroll
  for (int i = 0; i < 2; ++i)
#pragma unroll
    for (int j = 0; j < 2; ++j)
#pragma unroll
      for (int rg = 0; rg < 4; ++rg) {
        int m = m0 + wm + i * 16 + cm + rg;
        int n = n0 + wn + j * 16 + cn;
        Kw[((size_t)b * M_ + m) * N_ + n] = f2bf(expf(10.f * (acc[i][j][rg] - 1.f)));
      }
}

// One Sinkhorn iteration (u-step then v-step) in a single wide launch.
// Grid 1168 blocks, XCD-pinned: bid%8 = XCD; batch b = (bid%8) + 8*((bid/8)&1)
// so batch b's K (590 KB) stays in L2 of XCD b%8. Per batch 73 blocks:
//   roles 0..63  (u-blocks): 4 rows each, one per wave -- exact round-0 sink_u
//                body (9-term k-order lane sum + shfl tree + powf); after the
//                writes, one release-increment of the per-batch counter.
//   roles 64..72 (v-blocks): spin on the counter (round-4-verified barrier
//                pattern), stage u in LDS, then exact round-0 sink_v body.
// First iteration multiplies by v==1.0 (bit-identical to the no-multiply
// first step: x*1.0f == x).
__global__ __launch_bounds__(256) void sink_iter_kernel(
    const unsigned short* __restrict__ Kw, const float* __restrict__ mask,
    const float* __restrict__ msum, float* __restrict__ uu,
    float* __restrict__ vv, int* __restrict__ ctr, int it) {
  __shared__ float u_s[M_];
  __shared__ float part[4][64];

  const int bid = blockIdx.x;
  const int xcd = bid & 7;
  const int idx = bid >> 3;            // 0..145
  const int b = xcd + 8 * (idx & 1);   // batch, pinned to XCD b%8
  const int role = idx >> 1;           // 0..72
  const int t = threadIdx.x;
  const int lane = t & 63;
  const int w = t >> 6;

  if (role < 64) {
    // ---- u-block: row per wave ----
    const int row = b * M_ + role * 4 + w;
    const unsigned short* rp = Kw + (size_t)row * N_;
    const float* vb = vv + b * N_;
    float s = 0.f;
#pragma unroll
    for (int k = 0; k < 9; ++k) s += bf2f(rp[lane + 64 * k]) * vb[lane + 64 * k];
    s = wave_reduce(s);
    if (lane == 0) {
      float nu = mask[row] / (msum[b] + EPS_);
      uu[row] = powf(nu / (s + EPS_), FI_);
    }
    __syncthreads();
    if (t == 0) {
      __threadfence();
      __hip_atomic_fetch_add(&ctr[b * 5 + it], 1, __ATOMIC_RELEASE,
                             __HIP_MEMORY_SCOPE_AGENT);
    }
  } else {
    // ---- v-block: 64 columns; wave g sums rows g*64..g*64+63 ----
    const int vblk = role - 64;        // 0..8
    if (t == 0) {
      while (__hip_atomic_load(&ctr[b * 5 + it], __ATOMIC_ACQUIRE,
                               __HIP_MEMORY_SCOPE_AGENT) < 64)
        __builtin_amdgcn_s_sleep(2);
    }
    __syncthreads();
    __threadfence();                   // acquire: drop stale cached uu lines
    u_s[t] = uu[b * M_ + t];
    __syncthreads();
    const unsigned short* Kb2 = Kw + (size_t)b * M_ * N_;
    const int col = vblk * 64 + lane;
    float s = 0.f;
#pragma unroll 8
    for (int m = w * 64; m < (w + 1) * 64; ++m)
      s += bf2f(Kb2[(size_t)m * N_ + col]) * u_s[m];
    part[w][lane] = s;
    __syncthreads();
    if (t < 64) {
      float tot = part[0][t] + part[1][t] + part[2][t] + part[3][t];
      vv[b * N_ + vblk * 64 + t] = powf((1.f / (float)N_) / (tot + EPS_), FI_);
    }
  }
}

// Per (b,m) row: s1 = sum_n K*v, s2 = sum_n K*v*SL.
// partial[row] = -mask[row]*s2 / ((s1+EPS)*B*H*M).  (u cancels in row-norm.)
__global__ __launch_bounds__(256) void finloss_kernel(const unsigned short* __restrict__ Kw,
                                                      const float* __restrict__ SL,
                                                      const float* __restrict__ v,
                                                      const float* __restrict__ mask,
                                                      float* __restrict__ partial) {
  __shared__ float red[2][4];
  const int m = blockIdx.x;
  const int b = blockIdx.y;
  const int t = threadIdx.x;
  float s1 = 0.f, s2 = 0.f;
  if (t < N_ / 4) {
    const unsigned short* kp = Kw + ((size_t)b * M_ + m) * N_ + t * 4;
    ushort4 k4 = *(const ushort4*)kp;
    float4 v4 = *(const float4*)&v[b * N_ + t * 4];
    float4 sl4 = *(const float4*)&SL[((size_t)b * M_ + m) * N_ + t * 4];
    float kv0 = bf2f(k4.x) * v4.x, kv1 = bf2f(k4.y) * v4.y;
    float kv2 = bf2f(k4.z) * v4.z, kv3 = bf2f(k4.w) * v4.w;
    s1 = kv0 + kv1 + kv2 + kv3;
    s2 = kv0 * sl4.x + kv1 * sl4.y + kv2 * sl4.z + kv3 * sl4.w;
  }
  s1 = wave_reduce(s1);
  s2 = wave_reduce(s2);
  if ((t & 63) == 0) { red[0][t >> 6] = s1; red[1][t >> 6] = s2; }
  __syncthreads();
  if (t == 0) {
    float S1 = red[0][0] + red[0][1] + red[0][2] + red[0][3];
    float S2 = red[1][0] + red[1][1] + red[1][2] + red[1][3];
    int row = b * M_ + m;
    partial[row] = -mask[row] * S2 / ((S1 + EPS_) * (float)(B_ * H_ * M_));
  }
}

// Sum 4096 partials -> d_out[0]. Single block.
__global__ __launch_bounds__(256) void reduce_kernel(const float* __restrict__ partial,
                                                     float* __restrict__ out) {
  __shared__ float red[4];
  float s = 0.f;
  for (int i = threadIdx.x; i < B_ * M_; i += 256) s += partial[i];
  s = wave_reduce(s);
  if ((threadIdx.x & 63) == 0) red[threadIdx.x >> 6] = s;
  __syncthreads();
  if (threadIdx.x == 0) out[0] = red[0] + red[1] + red[2] + red[3];
}

extern "C" void kernel_launch(void* const* d_in, const int* in_sizes, int n_in,
                              void* d_out, int out_size, void* d_ws, size_t ws_size,
                              hipStream_t stream) {
  const float* student = (const float*)d_in[0];  // (B,H,M,N)
  const float* vis = (const float*)d_in[1];      // (B,N,D)
  const float* txt = (const float*)d_in[2];      // (B,M,D)
  const float* mask = (const float*)d_in[3];     // (B,M)
  float* out = (float*)d_out;

  char* p = (char*)d_ws;
  unsigned short* Kw = (unsigned short*)p; p += (size_t)B_ * M_ * N_ * 2;   // 4.7 MB
  unsigned short* xb = (unsigned short*)p; p += (size_t)B_ * N_ * D_ * 2;   // 18.9 MB
  unsigned short* yb = (unsigned short*)p; p += (size_t)B_ * M_ * D_ * 2;   // 8.4 MB
  float* SL = (float*)p;      p += (size_t)B_ * M_ * N_ * 4;                // 9.4 MB
  float* msum = (float*)p;    p += 256;
  float* uu = (float*)p;      p += (size_t)B_ * M_ * 4;
  float* vv = (float*)p;      p += (size_t)B_ * N_ * 4;
  float* partial = (float*)p; p += (size_t)B_ * M_ * 4;
  int* ctr = (int*)p;         p += 96 * 4;

  prep_kernel<<<NROWS / 4 + 4, 256, 0, stream>>>(vis, txt, mask, xb, yb, msum, vv, ctr);
  gemm_sumlog_kernel<<<GEMM_BLOCKS + SUMLOG_BLK, 256, 0, stream>>>(xb, yb, student, Kw, SL);
  for (int it = 0; it < 5; ++it)
    sink_iter_kernel<<<16 * 73, 256, 0, stream>>>(Kw, mask, msum, uu, vv, ctr, it);
  finloss_kernel<<<dim3(M_, B_), 256, 0, stream>>>(Kw, SL, vv, mask, partial);
  reduce_kernel<<<1, 256, 0, stream>>>(partial, out);
}

// Round 6
// 484.552 us; speedup vs baseline: 1.0226x; 1.0226x over previous
//
#include <hip/hip_runtime.h>
#include <math.h>

#define B_ 16
#define H_ 16
#define M_ 256
#define N_ 576
#define D_ 1024
#define BK 64
#define LDS_STRIDE (BK + 8)
#define NROWS (B_ * N_ + B_ * M_)         // 13312 feature rows
#define GEMM_BLOCKS (B_ * 4 * 9)          // 576 tiles

constexpr float EPS_ = 1e-8f;
constexpr float FI_ = 0.90909090909090906f;   // RHO/(RHO+EPSILON) = 1/1.1

typedef __bf16 bf16x8 __attribute__((ext_vector_type(8)));
typedef float f32x4 __attribute__((ext_vector_type(4)));

__device__ __forceinline__ float wave_reduce(float v) {
#pragma unroll
  for (int o = 32; o > 0; o >>= 1) v += __shfl_down(v, o, 64);
  return v;
}

__device__ __forceinline__ unsigned short f2bf(float f) {
  union { float f; unsigned u; } a; a.f = f;
  unsigned r = a.u + 0x7fff + ((a.u >> 16) & 1);   // RNE
  return (unsigned short)(r >> 16);
}

__device__ __forceinline__ float bf2f(unsigned short u) {
  union { unsigned u; float f; } a; a.u = ((unsigned)u) << 16;
  return a.f;
}

// L2-normalize+bf16-cast vis (B*N rows) and txt (B*M rows), one wave per row;
// trailing 4 blocks: masksum[b] and vv := 1.0 (for the first sink iteration).
__global__ __launch_bounds__(256) void prep_kernel(const float* __restrict__ vis,
                                                   const float* __restrict__ txt,
                                                   const float* __restrict__ mask,
                                                   unsigned short* __restrict__ xb,
                                                   unsigned short* __restrict__ yb,
                                                   float* __restrict__ masksum,
                                                   float* __restrict__ vv) {
  const int bid = blockIdx.x;
  const int lane = threadIdx.x & 63;
  if (bid < NROWS / 4) {
    int wave = bid * 4 + (threadIdx.x >> 6);
    const float* src;
    unsigned short* dst;
    if (wave < B_ * N_) {
      src = vis + (size_t)wave * D_;
      dst = xb + (size_t)wave * D_;
    } else {
      int r = wave - B_ * N_;
      src = txt + (size_t)r * D_;
      dst = yb + (size_t)r * D_;
    }
    float4 v[4];
    float s = 0.f;
#pragma unroll
    for (int it = 0; it < 4; ++it) {
      v[it] = *(const float4*)&src[it * 256 + lane * 4];
      s += v[it].x * v[it].x + v[it].y * v[it].y + v[it].z * v[it].z + v[it].w * v[it].w;
    }
    s = wave_reduce(s);
    s = __shfl(s, 0, 64);
    float inv = rsqrtf(s + 1e-12f);
#pragma unroll
    for (int it = 0; it < 4; ++it) {
      ushort4 pk;
      pk.x = f2bf(v[it].x * inv);
      pk.y = f2bf(v[it].y * inv);
      pk.z = f2bf(v[it].z * inv);
      pk.w = f2bf(v[it].w * inv);
      *(ushort4*)&dst[it * 256 + lane * 4] = pk;
    }
  } else {
    const int g = bid - NROWS / 4;                       // 0..3
    for (int i = threadIdx.x; i < 4 * N_; i += 256) vv[g * 4 * N_ + i] = 1.f;
    int b = g * 4 + (threadIdx.x >> 6);                  // 0..15
    float4 mv = *(const float4*)&mask[b * M_ + lane * 4];
    float s = wave_reduce(mv.x + mv.y + mv.z + mv.w);
    if (lane == 0) masksum[b] = s;
  }
}

// K[b,m,n] = bf16(exp(10*(dot(y,x)-1))), bf16 MFMA 16x16x32, 64x64 tile/block,
// 4 waves each computing a 32x32 sub-tile (verbatim verified round-0 body).
__global__ __launch_bounds__(256) void gemm_k_mfma(const unsigned short* __restrict__ xb,
                                                   const unsigned short* __restrict__ yb,
                                                   unsigned short* __restrict__ Kw) {
  __shared__ unsigned short As[64][LDS_STRIDE];  // y rows (m)
  __shared__ unsigned short Bs[64][LDS_STRIDE];  // x rows (n)
  const int tile = blockIdx.x;
  const int b = tile / 36;
  const int rem = tile - b * 36;
  const int m0 = (rem / 9) * 64;
  const int n0 = (rem - (rem / 9) * 9) * 64;
  const unsigned short* Y = yb + (size_t)b * M_ * D_;
  const unsigned short* X = xb + (size_t)b * N_ * D_;
  const int t = threadIdx.x;
  const int lane = t & 63;
  const int w = t >> 6;
  const int wm = (w & 1) * 32;
  const int wn = (w >> 1) * 32;
  const int lr = t >> 3;           // 0..31 staging row
  const int lc = (t & 7) * 8;      // staging col (bf16 units, 16B chunks)
  const int fr = lane & 15;        // fragment row within 16
  const int fk = (lane >> 4) * 8;  // fragment k offset

  f32x4 acc[2][2] = {};
  for (int k0 = 0; k0 < D_; k0 += BK) {
#pragma unroll
    for (int p = 0; p < 2; ++p) {
      *(uint4*)&As[lr + 32 * p][lc] = *(const uint4*)&Y[(size_t)(m0 + lr + 32 * p) * D_ + k0 + lc];
      *(uint4*)&Bs[lr + 32 * p][lc] = *(const uint4*)&X[(size_t)(n0 + lr + 32 * p) * D_ + k0 + lc];
    }
    __syncthreads();
#pragma unroll
    for (int ks = 0; ks < BK; ks += 32) {
      bf16x8 a[2], bfr[2];
#pragma unroll
      for (int i = 0; i < 2; ++i) {
        a[i] = *(const bf16x8*)&As[wm + i * 16 + fr][ks + fk];
        bfr[i] = *(const bf16x8*)&Bs[wn + i * 16 + fr][ks + fk];
      }
#pragma unroll
      for (int i = 0; i < 2; ++i)
#pragma unroll
        for (int j = 0; j < 2; ++j)
          acc[i][j] = __builtin_amdgcn_mfma_f32_16x16x32_bf16(a[i], bfr[j], acc[i][j], 0, 0, 0);
    }
    __syncthreads();
  }

  // C/D layout: m = (lane>>4)*4 + reg, n = lane&15
  const int cm = (lane >> 4) * 4;
  const int cn = lane & 15;
#pragma unroll
  for (int i = 0; i < 2; ++i)
#pragma unroll
    for (int j = 0; j < 2; ++j)
#pragma unroll
      for (int rg = 0; rg < 4; ++rg) {
        int m = m0 + wm + i * 16 + cm + rg;
        int n = n0 + wn + j * 16 + cn;
        Kw[((size_t)b * M_ + m) * N_ + n] = f2bf(expf(10.f * (acc[i][j][rg] - 1.f)));
      }
}

// One full Sinkhorn iteration (u-step + v-step) with NO cross-block sync:
// 144 blocks, block (b, vblk) owns output columns vblk*64..+63 of batch b.
// Phase A: the block computes the ENTIRE u vector of its batch (redundant
//   across the 9 blocks of the batch -- cheap, latency-bound): wave w reduces
//   rows w*64..w*64+63 with the exact round-0 per-row op (9-term k-order lane
//   sum + 64-lane shfl tree), then 256 threads apply the exact powf.
// Phase B: verbatim round-0 sink_v body (wave w sums rows w*64.. sequentially
//   for its 64 columns, quarters combined in exact order), u read from LDS.
// v is re-read from global each launch (kernel boundary = the only sync).
// First iteration multiplies by v==1.0 from prep (x*1.0f is bit-exact).
__global__ __launch_bounds__(256) void sink_uv_kernel(
    const unsigned short* __restrict__ Kw, const float* __restrict__ mask,
    const float* __restrict__ msum, float* __restrict__ vv) {
  __shared__ float v_s[N_];
  __shared__ float nu_s[M_];
  __shared__ float sred[M_];
  __shared__ float u_s[M_];
  __shared__ float part[4][64];
  const int b = blockIdx.x / 9;
  const int vblk = blockIdx.x - b * 9;
  const int t = threadIdx.x;
  const int lane = t & 63;
  const int w = t >> 6;
  const unsigned short* Kb = Kw + (size_t)b * M_ * N_;

  nu_s[t] = mask[b * M_ + t] / (msum[b] + EPS_);
  for (int n = t; n < N_; n += 256) v_s[n] = vv[b * N_ + n];
  __syncthreads();

  // ---- Phase A: u for all 256 rows; wave w rows w*64..w*64+63 ----
#pragma unroll 4
  for (int r = 0; r < 64; ++r) {
    const int m = w * 64 + r;
    const unsigned short* rp = Kb + (size_t)m * N_;
    float s = 0.f;
#pragma unroll
    for (int k = 0; k < 9; ++k) s += bf2f(rp[lane + 64 * k]) * v_s[lane + 64 * k];
    s = wave_reduce(s);
    if (lane == 0) sred[m] = s;
  }
  __syncthreads();
  u_s[t] = powf(nu_s[t] / (sred[t] + EPS_), FI_);
  __syncthreads();

  // ---- Phase B: exact round-0 sink_v body for cols vblk*64..+63 ----
  const int col = vblk * 64 + lane;
  float s = 0.f;
#pragma unroll 8
  for (int m = w * 64; m < (w + 1) * 64; ++m)
    s += bf2f(Kb[(size_t)m * N_ + col]) * u_s[m];
  part[w][lane] = s;
  __syncthreads();
  if (t < 64) {
    float tot = part[0][t] + part[1][t] + part[2][t] + part[3][t];
    vv[b * N_ + vblk * 64 + t] = powf((1.f / (float)N_) / (tot + EPS_), FI_);
  }
}

// Per (b,m) row, with SL computed INLINE (saves the 9.4MB SL round-trip and
// the separate sumlog kernel): sl[n] = sum_h log(student[b,h,m,n]+EPS) in
// ascending-h order (bit-identical to the old sumlog), then
// s1 = sum_n K*v, s2 = sum_n K*v*sl, exact round-0 reduction pattern.
__global__ __launch_bounds__(256) void finloss_kernel(
    const unsigned short* __restrict__ Kw, const float* __restrict__ student,
    const float* __restrict__ v, const float* __restrict__ mask,
    float* __restrict__ partial) {
  __shared__ float red[2][4];
  const int m = blockIdx.x;
  const int b = blockIdx.y;
  const int t = threadIdx.x;
  float s1 = 0.f, s2 = 0.f;
  if (t < N_ / 4) {
    const float* st = student + (size_t)b * H_ * M_ * N_ + (size_t)m * N_ + t * 4;
    float4 sl = {0.f, 0.f, 0.f, 0.f};
#pragma unroll
    for (int h = 0; h < H_; ++h) {
      float4 s4 = *(const float4*)&st[(size_t)h * M_ * N_];
      sl.x += __logf(s4.x + EPS_);
      sl.y += __logf(s4.y + EPS_);
      sl.z += __logf(s4.z + EPS_);
      sl.w += __logf(s4.w + EPS_);
    }
    ushort4 k4 = *(const ushort4*)&Kw[((size_t)b * M_ + m) * N_ + t * 4];
    float4 v4 = *(const float4*)&v[b * N_ + t * 4];
    float kv0 = bf2f(k4.x) * v4.x, kv1 = bf2f(k4.y) * v4.y;
    float kv2 = bf2f(k4.z) * v4.z, kv3 = bf2f(k4.w) * v4.w;
    s1 = kv0 + kv1 + kv2 + kv3;
    s2 = kv0 * sl.x + kv1 * sl.y + kv2 * sl.z + kv3 * sl.w;
  }
  s1 = wave_reduce(s1);
  s2 = wave_reduce(s2);
  if ((t & 63) == 0) { red[0][t >> 6] = s1; red[1][t >> 6] = s2; }
  __syncthreads();
  if (t == 0) {
    float S1 = red[0][0] + red[0][1] + red[0][2] + red[0][3];
    float S2 = red[1][0] + red[1][1] + red[1][2] + red[1][3];
    int row = b * M_ + m;
    partial[row] = -mask[row] * S2 / ((S1 + EPS_) * (float)(B_ * H_ * M_));
  }
}

// Sum 4096 partials -> d_out[0]. Single block.
__global__ __launch_bounds__(256) void reduce_kernel(const float* __restrict__ partial,
                                                     float* __restrict__ out) {
  __shared__ float red[4];
  float s = 0.f;
  for (int i = threadIdx.x; i < B_ * M_; i += 256) s += partial[i];
  s = wave_reduce(s);
  if ((threadIdx.x & 63) == 0) red[threadIdx.x >> 6] = s;
  __syncthreads();
  if (threadIdx.x == 0) out[0] = red[0] + red[1] + red[2] + red[3];
}

extern "C" void kernel_launch(void* const* d_in, const int* in_sizes, int n_in,
                              void* d_out, int out_size, void* d_ws, size_t ws_size,
                              hipStream_t stream) {
  const float* student = (const float*)d_in[0];  // (B,H,M,N)
  const float* vis = (const float*)d_in[1];      // (B,N,D)
  const float* txt = (const float*)d_in[2];      // (B,M,D)
  const float* mask = (const float*)d_in[3];     // (B,M)
  float* out = (float*)d_out;

  char* p = (char*)d_ws;
  unsigned short* Kw = (unsigned short*)p; p += (size_t)B_ * M_ * N_ * 2;   // 4.7 MB
  unsigned short* xb = (unsigned short*)p; p += (size_t)B_ * N_ * D_ * 2;   // 18.9 MB
  unsigned short* yb = (unsigned short*)p; p += (size_t)B_ * M_ * D_ * 2;   // 8.4 MB
  float* msum = (float*)p;    p += 256;
  float* vv = (float*)p;      p += (size_t)B_ * N_ * 4;
  float* partial = (float*)p; p += (size_t)B_ * M_ * 4;

  prep_kernel<<<NROWS / 4 + 4, 256, 0, stream>>>(vis, txt, mask, xb, yb, msum, vv);
  gemm_k_mfma<<<GEMM_BLOCKS, 256, 0, stream>>>(xb, yb, Kw);
  for (int it = 0; it < 5; ++it)
    sink_uv_kernel<<<B_ * 9, 256, 0, stream>>>(Kw, mask, msum, vv);
  finloss_kernel<<<dim3(M_, B_), 256, 0, stream>>>(Kw, student, vv, mask, partial);
  reduce_kernel<<<1, 256, 0, stream>>>(partial, out);
}

// Round 7
// 337.626 us; speedup vs baseline: 1.4676x; 1.4352x over previous
//
#include <hip/hip_runtime.h>
#include <math.h>

#define B_ 16
#define H_ 16
#define M_ 256
#define N_ 576
#define D_ 1024
#define BK 64
#define LDS_STRIDE (BK + 8)
#define NROWS (B_ * N_ + B_ * M_)   // 13312 feature rows to normalize

#define SL_TOTAL (B_ * M_)          // 4096 sumlog row-units
#define SL_CHUNK 410                // per sink launch (10 launches x 410 >= 4096)

constexpr float EPS_ = 1e-8f;
constexpr float FI_ = 0.90909090909090906f;   // RHO/(RHO+EPSILON) = 1/1.1

typedef __bf16 bf16x8 __attribute__((ext_vector_type(8)));
typedef float f32x4 __attribute__((ext_vector_type(4)));

__device__ __forceinline__ float wave_reduce(float v) {
#pragma unroll
  for (int o = 32; o > 0; o >>= 1) v += __shfl_down(v, o, 64);
  return v;
}

__device__ __forceinline__ unsigned short f2bf(float f) {
  union { float f; unsigned u; } a; a.f = f;
  unsigned r = a.u + 0x7fff + ((a.u >> 16) & 1);   // RNE
  return (unsigned short)(r >> 16);
}

__device__ __forceinline__ float bf2f(unsigned short u) {
  union { unsigned u; float f; } a; a.u = ((unsigned)u) << 16;
  return a.f;
}

// SL row-unit: SL[b,m,n] = sum_h log(student[b,h,m,n]+EPS) for one (b,m) row.
// EXACT round-0 sumlog body (ascending-h order, float4 per thread, t<144).
__device__ __forceinline__ void sumlog_unit(const float* __restrict__ student,
                                            float* __restrict__ SL, int unit,
                                            int t) {
  if (t >= N_ / 4) return;
  const int b = unit >> 8;
  const int m = unit & 255;
  const float* st = student + ((size_t)b * H_ * M_ + m) * N_ + t * 4;
  float4 acc = {0.f, 0.f, 0.f, 0.f};
#pragma unroll
  for (int h = 0; h < H_; ++h) {
    float4 s4 = *(const float4*)&st[(size_t)h * M_ * N_];
    acc.x += __logf(s4.x + EPS_);
    acc.y += __logf(s4.y + EPS_);
    acc.z += __logf(s4.z + EPS_);
    acc.w += __logf(s4.w + EPS_);
  }
  *(float4*)&SL[((size_t)b * M_ + m) * N_ + t * 4] = acc;
}

// One launch: L2-normalize+bf16-cast vis (B*N rows) and txt (B*M rows), one wave
// per row; trailing 4 blocks compute masksum[b] = sum_m mask[b,m].
__global__ __launch_bounds__(256) void prep_kernel(const float* __restrict__ vis,
                                                   const float* __restrict__ txt,
                                                   const float* __restrict__ mask,
                                                   unsigned short* __restrict__ xb,
                                                   unsigned short* __restrict__ yb,
                                                   float* __restrict__ masksum) {
  const int bid = blockIdx.x;
  const int lane = threadIdx.x & 63;
  if (bid < NROWS / 4) {
    int wave = bid * 4 + (threadIdx.x >> 6);
    const float* src;
    unsigned short* dst;
    if (wave < B_ * N_) {
      src = vis + (size_t)wave * D_;
      dst = xb + (size_t)wave * D_;
    } else {
      int r = wave - B_ * N_;
      src = txt + (size_t)r * D_;
      dst = yb + (size_t)r * D_;
    }
    float4 v[4];
    float s = 0.f;
#pragma unroll
    for (int it = 0; it < 4; ++it) {
      v[it] = *(const float4*)&src[it * 256 + lane * 4];
      s += v[it].x * v[it].x + v[it].y * v[it].y + v[it].z * v[it].z + v[it].w * v[it].w;
    }
    s = wave_reduce(s);
    s = __shfl(s, 0, 64);
    float inv = rsqrtf(s + 1e-12f);
#pragma unroll
    for (int it = 0; it < 4; ++it) {
      ushort4 pk;
      pk.x = f2bf(v[it].x * inv);
      pk.y = f2bf(v[it].y * inv);
      pk.z = f2bf(v[it].z * inv);
      pk.w = f2bf(v[it].w * inv);
      *(ushort4*)&dst[it * 256 + lane * 4] = pk;
    }
  } else {
    int b = (bid - NROWS / 4) * 4 + (threadIdx.x >> 6);  // 0..15
    float4 mv = *(const float4*)&mask[b * M_ + lane * 4];
    float s = wave_reduce(mv.x + mv.y + mv.z + mv.w);
    if (lane == 0) masksum[b] = s;
  }
}

// K[b,m,n] = bf16(exp(10*(dot(yb[b,m],xb[b,n]) - 1))), bf16 MFMA 16x16x32,
// 64x64 tile/block, 4 waves each computing a 32x32 sub-tile (2x2 frags).
__global__ __launch_bounds__(256) void gemm_k_mfma(const unsigned short* __restrict__ xb,
                                                   const unsigned short* __restrict__ yb,
                                                   unsigned short* __restrict__ Kw) {
  __shared__ unsigned short As[64][LDS_STRIDE];  // y rows (m)
  __shared__ unsigned short Bs[64][LDS_STRIDE];  // x rows (n)
  const int b = blockIdx.z;
  const int m0 = blockIdx.y * 64;
  const int n0 = blockIdx.x * 64;
  const unsigned short* Y = yb + (size_t)b * M_ * D_;
  const unsigned short* X = xb + (size_t)b * N_ * D_;
  const int t = threadIdx.x;
  const int lane = t & 63;
  const int w = t >> 6;
  const int wm = (w & 1) * 32;
  const int wn = (w >> 1) * 32;
  const int lr = t >> 3;           // 0..31 staging row
  const int lc = (t & 7) * 8;      // staging col (bf16 units, 16B chunks)
  const int fr = lane & 15;        // fragment row within 16
  const int fk = (lane >> 4) * 8;  // fragment k offset

  f32x4 acc[2][2] = {};
  for (int k0 = 0; k0 < D_; k0 += BK) {
#pragma unroll
    for (int p = 0; p < 2; ++p) {
      *(uint4*)&As[lr + 32 * p][lc] = *(const uint4*)&Y[(size_t)(m0 + lr + 32 * p) * D_ + k0 + lc];
      *(uint4*)&Bs[lr + 32 * p][lc] = *(const uint4*)&X[(size_t)(n0 + lr + 32 * p) * D_ + k0 + lc];
    }
    __syncthreads();
#pragma unroll
    for (int ks = 0; ks < BK; ks += 32) {
      bf16x8 a[2], bfr[2];
#pragma unroll
      for (int i = 0; i < 2; ++i) {
        a[i] = *(const bf16x8*)&As[wm + i * 16 + fr][ks + fk];
        bfr[i] = *(const bf16x8*)&Bs[wn + i * 16 + fr][ks + fk];
      }
#pragma unroll
      for (int i = 0; i < 2; ++i)
#pragma unroll
        for (int j = 0; j < 2; ++j)
          acc[i][j] = __builtin_amdgcn_mfma_f32_16x16x32_bf16(a[i], bfr[j], acc[i][j], 0, 0, 0);
    }
    __syncthreads();
  }

  // C/D layout: m = (lane>>4)*4 + reg, n = lane&15
  const int cm = (lane >> 4) * 4;
  const int cn = lane & 15;
#pragma unroll
  for (int i = 0; i < 2; ++i)
#pragma unroll
    for (int j = 0; j < 2; ++j)
#pragma unroll
      for (int rg = 0; rg < 4; ++rg) {
        int m = m0 + wm + i * 16 + cm + rg;
        int n = n0 + wn + j * 16 + cn;
        Kw[((size_t)b * M_ + m) * N_ + n] = f2bf(expf(10.f * (acc[i][j][rg] - 1.f)));
      }
}

// ---------- Sinkhorn: R0's wide shallow launches, each carrying a 410-unit
// ---------- sumlog chunk as extra blocks (HBM work rides the idle BW). ------

// first u-step (v == 1): blocks x<64 are u-role (verbatim R0 body);
// x>=64 are sumlog units chunk*410 + (x-64)*16 + y.
__global__ __launch_bounds__(256) void sink_u_first(const unsigned short* __restrict__ Kw,
                                                    const float* __restrict__ mask,
                                                    const float* __restrict__ masksum,
                                                    float* __restrict__ u,
                                                    const float* __restrict__ student,
                                                    float* __restrict__ SL, int chunk) {
  if (blockIdx.x >= M_ / 4) {
    const int idx = (blockIdx.x - M_ / 4) * B_ + blockIdx.y;
    const int unit = chunk * SL_CHUNK + idx;
    if (idx < SL_CHUNK && unit < SL_TOTAL)
      sumlog_unit(student, SL, unit, threadIdx.x);
    return;
  }
  const int b = blockIdx.y;
  const int row = blockIdx.x * 4 + (threadIdx.x >> 6);
  const int lane = threadIdx.x & 63;
  const unsigned short* rowp = Kw + ((size_t)b * M_ + row) * N_;
  float s = 0.f;
#pragma unroll
  for (int k = 0; k < 9; ++k) s += bf2f(rowp[lane + 64 * k]);
  s = wave_reduce(s);
  if (lane == 0) {
    int idx = b * M_ + row;
    float nu = mask[idx] / (masksum[b] + EPS_);
    u[idx] = powf(nu / (s + EPS_), FI_);
  }
}

// u-step: u = (nu/(K·v + EPS))^fi  (verbatim R0 body; + sumlog chunk blocks)
__global__ __launch_bounds__(256) void sink_u(const unsigned short* __restrict__ Kw,
                                              const float* __restrict__ v,
                                              const float* __restrict__ mask,
                                              const float* __restrict__ masksum,
                                              float* __restrict__ u,
                                              const float* __restrict__ student,
                                              float* __restrict__ SL, int chunk) {
  if (blockIdx.x >= M_ / 4) {
    const int idx = (blockIdx.x - M_ / 4) * B_ + blockIdx.y;
    const int unit = chunk * SL_CHUNK + idx;
    if (idx < SL_CHUNK && unit < SL_TOTAL)
      sumlog_unit(student, SL, unit, threadIdx.x);
    return;
  }
  const int b = blockIdx.y;
  const int row = blockIdx.x * 4 + (threadIdx.x >> 6);
  const int lane = threadIdx.x & 63;
  const unsigned short* rowp = Kw + ((size_t)b * M_ + row) * N_;
  const float* vb = v + b * N_;
  float s = 0.f;
#pragma unroll
  for (int k = 0; k < 9; ++k) s += bf2f(rowp[lane + 64 * k]) * vb[lane + 64 * k];
  s = wave_reduce(s);
  if (lane == 0) {
    int idx = b * M_ + row;
    float nu = mask[idx] / (masksum[b] + EPS_);
    u[idx] = powf(nu / (s + EPS_), FI_);
  }
}

// v-step: v = (mu/(K^T·u + EPS))^fi  (verbatim R0 body; + sumlog chunk blocks)
__global__ __launch_bounds__(256) void sink_v(const unsigned short* __restrict__ Kw,
                                              const float* __restrict__ u,
                                              float* __restrict__ v,
                                              const float* __restrict__ student,
                                              float* __restrict__ SL, int chunk) {
  if (blockIdx.x >= N_ / 64) {
    const int idx = (blockIdx.x - N_ / 64) * B_ + blockIdx.y;
    const int unit = chunk * SL_CHUNK + idx;
    if (idx < SL_CHUNK && unit < SL_TOTAL)
      sumlog_unit(student, SL, unit, threadIdx.x);
    return;
  }
  __shared__ float part[4][64];
  const int b = blockIdx.y;
  const int n0 = blockIdx.x * 64;
  const int col = n0 + (threadIdx.x & 63);
  const int g = threadIdx.x >> 6;
  const unsigned short* Kb = Kw + (size_t)b * M_ * N_;
  const float* ub = u + b * M_;
  float s = 0.f;
#pragma unroll 8
  for (int m = g * 64; m < (g + 1) * 64; ++m) s += bf2f(Kb[(size_t)m * N_ + col]) * ub[m];
  part[g][threadIdx.x & 63] = s;
  __syncthreads();
  if (threadIdx.x < 64) {
    float tot = part[0][threadIdx.x] + part[1][threadIdx.x] +
                part[2][threadIdx.x] + part[3][threadIdx.x];
    v[b * N_ + n0 + threadIdx.x] = powf((1.f / (float)N_) / (tot + EPS_), FI_);
  }
}

// Per (b,m) row: s1 = sum_n K*v, s2 = sum_n K*v*SL.
// partial[row] = -mask[row]*s2 / ((s1+EPS)*B*H*M).  (u cancels in row-norm.)
__global__ __launch_bounds__(256) void finloss_kernel(const unsigned short* __restrict__ Kw,
                                                      const float* __restrict__ SL,
                                                      const float* __restrict__ v,
                                                      const float* __restrict__ mask,
                                                      float* __restrict__ partial) {
  __shared__ float red[2][4];
  const int m = blockIdx.x;
  const int b = blockIdx.y;
  const int t = threadIdx.x;
  float s1 = 0.f, s2 = 0.f;
  if (t < N_ / 4) {
    const unsigned short* kp = Kw + ((size_t)b * M_ + m) * N_ + t * 4;
    ushort4 k4 = *(const ushort4*)kp;
    float4 v4 = *(const float4*)&v[b * N_ + t * 4];
    float4 sl4 = *(const float4*)&SL[((size_t)b * M_ + m) * N_ + t * 4];
    float kv0 = bf2f(k4.x) * v4.x, kv1 = bf2f(k4.y) * v4.y;
    float kv2 = bf2f(k4.z) * v4.z, kv3 = bf2f(k4.w) * v4.w;
    s1 = kv0 + kv1 + kv2 + kv3;
    s2 = kv0 * sl4.x + kv1 * sl4.y + kv2 * sl4.z + kv3 * sl4.w;
  }
  s1 = wave_reduce(s1);
  s2 = wave_reduce(s2);
  if ((t & 63) == 0) { red[0][t >> 6] = s1; red[1][t >> 6] = s2; }
  __syncthreads();
  if (t == 0) {
    float S1 = red[0][0] + red[0][1] + red[0][2] + red[0][3];
    float S2 = red[1][0] + red[1][1] + red[1][2] + red[1][3];
    int row = b * M_ + m;
    partial[row] = -mask[row] * S2 / ((S1 + EPS_) * (float)(B_ * H_ * M_));
  }
}

// Sum 4096 partials -> d_out[0]. Single block.
__global__ __launch_bounds__(256) void reduce_kernel(const float* __restrict__ partial,
                                                     float* __restrict__ out) {
  __shared__ float red[4];
  float s = 0.f;
  for (int i = threadIdx.x; i < B_ * M_; i += 256) s += partial[i];
  s = wave_reduce(s);
  if ((threadIdx.x & 63) == 0) red[threadIdx.x >> 6] = s;
  __syncthreads();
  if (threadIdx.x == 0) out[0] = red[0] + red[1] + red[2] + red[3];
}

extern "C" void kernel_launch(void* const* d_in, const int* in_sizes, int n_in,
                              void* d_out, int out_size, void* d_ws, size_t ws_size,
                              hipStream_t stream) {
  const float* student = (const float*)d_in[0];  // (B,H,M,N)
  const float* vis = (const float*)d_in[1];      // (B,N,D)
  const float* txt = (const float*)d_in[2];      // (B,M,D)
  const float* mask = (const float*)d_in[3];     // (B,M)
  float* out = (float*)d_out;

  char* p = (char*)d_ws;
  unsigned short* Kb = (unsigned short*)p; p += (size_t)B_ * M_ * N_ * 2;   // 4.7 MB
  unsigned short* xb = (unsigned short*)p; p += (size_t)B_ * N_ * D_ * 2;   // 18.9 MB
  unsigned short* yb = (unsigned short*)p; p += (size_t)B_ * M_ * D_ * 2;   // 8.4 MB
  float* SL = (float*)p;      p += (size_t)B_ * M_ * N_ * 4;                // 9.4 MB
  float* vv = (float*)p;      p += B_ * N_ * 4;
  float* uu = (float*)p;      p += B_ * M_ * 4;
  float* msum = (float*)p;    p += B_ * 4;
  float* partial = (float*)p; p += B_ * M_ * 4;

  // sumlog chunk grids: 410 units / launch, 16-y-major packing
  const int UXTRA = (SL_CHUNK + B_ - 1) / B_;   // 26 extra x-blocks

  prep_kernel<<<NROWS / 4 + 4, 256, 0, stream>>>(vis, txt, mask, xb, yb, msum);
  gemm_k_mfma<<<dim3(N_ / 64, M_ / 64, B_), 256, 0, stream>>>(xb, yb, Kb);

  sink_u_first<<<dim3(M_ / 4 + UXTRA, B_), 256, 0, stream>>>(Kb, mask, msum, uu,
                                                             student, SL, 0);
  sink_v<<<dim3(N_ / 64 + UXTRA, B_), 256, 0, stream>>>(Kb, uu, vv, student, SL, 1);
  for (int it = 1; it < 5; ++it) {
    sink_u<<<dim3(M_ / 4 + UXTRA, B_), 256, 0, stream>>>(Kb, vv, mask, msum, uu,
                                                         student, SL, 2 * it);
    sink_v<<<dim3(N_ / 64 + UXTRA, B_), 256, 0, stream>>>(Kb, uu, vv, student, SL,
                                                          2 * it + 1);
  }

  finloss_kernel<<<dim3(M_, B_), 256, 0, stream>>>(Kb, SL, vv, mask, partial);
  reduce_kernel<<<1, 256, 0, stream>>>(partial, out);
}